// Round 3
// baseline (1138.034 us; speedup 1.0000x reference)
//
#include <hip/hip_runtime.h>

#define TOKENS 4096
#define DDIM   2048
#define HDIM   1024
#define NEXP   8
#define GK     2048
#define GN     2048

typedef __bf16 bf16_t;
typedef __bf16 bf16x8 __attribute__((ext_vector_type(8)));
typedef __bf16 bf16x4 __attribute__((ext_vector_type(4)));
typedef float  f32x4  __attribute__((ext_vector_type(4)));

__device__ inline void gld_lds16(const bf16_t* g, bf16_t* l) {
  __builtin_amdgcn_global_load_lds(
      (const __attribute__((address_space(1))) void*)g,
      (__attribute__((address_space(3))) void*)l, 16, 0, 0);
}

// ---------------- fused routing + X fp32->bf16 convert ----------------
// One wave per token: converts its 2048-float row to bf16 AND computes both gates.
__global__ __launch_bounds__(256)
void k_routing_cvt(const float* __restrict__ vec,
                   const float* __restrict__ Wg, const float* __restrict__ bg,
                   const float* __restrict__ Wf, const float* __restrict__ bfv,
                   const float* __restrict__ wgt,
                   float* __restrict__ c0, float* __restrict__ c1,
                   bf16_t* __restrict__ Xbf)
{
  const int wave = threadIdx.x >> 6;
  const int lane = threadIdx.x & 63;
  const int m = blockIdx.x * 4 + wave;
  const float* v = vec + (size_t)m * DDIM;
  bf16_t* xo = Xbf + (size_t)m * DDIM;

  float ag[NEXP], af[NEXP];
#pragma unroll
  for (int e = 0; e < NEXP; ++e) { ag[e] = 0.f; af[e] = 0.f; }

#pragma unroll
  for (int j = 0; j < 8; ++j) {
    const int base = j * 256 + lane * 4;
    const float4 x = *(const float4*)(v + base);
    bf16x4 o; o[0] = (bf16_t)x.x; o[1] = (bf16_t)x.y; o[2] = (bf16_t)x.z; o[3] = (bf16_t)x.w;
    *(bf16x4*)(xo + base) = o;
    const float xs[4] = {x.x, x.y, x.z, x.w};
    if (j < 4) {
#pragma unroll
      for (int tt = 0; tt < 4; ++tt) {
        const float4 w0 = *(const float4*)(Wg + (base + tt) * NEXP);
        const float4 w1 = *(const float4*)(Wg + (base + tt) * NEXP + 4);
        ag[0] += xs[tt] * w0.x; ag[1] += xs[tt] * w0.y; ag[2] += xs[tt] * w0.z; ag[3] += xs[tt] * w0.w;
        ag[4] += xs[tt] * w1.x; ag[5] += xs[tt] * w1.y; ag[6] += xs[tt] * w1.z; ag[7] += xs[tt] * w1.w;
      }
    } else {
#pragma unroll
      for (int tt = 0; tt < 4; ++tt) {
        const float4 w0 = *(const float4*)(Wf + (base - HDIM + tt) * NEXP);
        const float4 w1 = *(const float4*)(Wf + (base - HDIM + tt) * NEXP + 4);
        af[0] += xs[tt] * w0.x; af[1] += xs[tt] * w0.y; af[2] += xs[tt] * w0.z; af[3] += xs[tt] * w0.w;
        af[4] += xs[tt] * w1.x; af[5] += xs[tt] * w1.y; af[6] += xs[tt] * w1.z; af[7] += xs[tt] * w1.w;
      }
    }
  }
#pragma unroll
  for (int e = 0; e < NEXP; ++e) {
#pragma unroll
    for (int off = 32; off >= 1; off >>= 1) {
      ag[e] += __shfl_xor(ag[e], off, 64);
      af[e] += __shfl_xor(af[e], off, 64);
    }
  }
  if (lane == 0) {
    float g[NEXP], f[NEXP];
    float mg = -1e30f, mf = -1e30f;
#pragma unroll
    for (int e = 0; e < NEXP; ++e) {
      g[e] = ag[e] + bg[e]; mg = fmaxf(mg, g[e]);
      f[e] = af[e] + bfv[e]; mf = fmaxf(mf, f[e]);
    }
    float sg = 0.f, sf = 0.f;
#pragma unroll
    for (int e = 0; e < NEXP; ++e) {
      g[e] = expf(g[e] - mg); sg += g[e];
      f[e] = expf(f[e] - mf); sf += f[e];
    }
    const float rg = 1.f / sg, rf = 1.f / sf;
#pragma unroll
    for (int e = 0; e < NEXP; ++e) { g[e] *= rg; f[e] *= rf; }
    int i1 = 0;
#pragma unroll
    for (int e = 1; e < NEXP; ++e) if (g[e] > g[i1]) i1 = e;
    int i2 = (i1 == 0) ? 1 : 0;
#pragma unroll
    for (int e = 0; e < NEXP; ++e) if (e != i1 && g[e] > g[i2]) i2 = e;
    const float w0 = wgt[0], w1 = wgt[1];
#pragma unroll
    for (int e = 0; e < NEXP; ++e) {
      c0[e * TOKENS + m] = (e == i1 || e == i2) ? w0 * g[e] : 0.f;
      c1[e * TOKENS + m] = w1 * f[e];
    }
  }
}

// ---------------- fp32 W[k][n] -> bf16 Wt[n][k], both tensors in one launch ----------------
// grid.z = 2*perTensor: z < perTensor -> (A,At), else (B,Bt); expert = z % perTensor
#define TP 68
__global__ __launch_bounds__(256)
void k_cvt_wt(const float* __restrict__ WA, const float* __restrict__ WB,
              bf16_t* __restrict__ WAt, bf16_t* __restrict__ WBt, const int perTensor)
{
  __shared__ __attribute__((aligned(16))) bf16_t tile[64 * TP];
  const int z = blockIdx.z;
  const int e = z % perTensor;
  const size_t eoff = (size_t)e * DDIM * DDIM;
  const float* w = ((z < perTensor) ? WA : WB) + eoff;
  bf16_t* wt = ((z < perTensor) ? WAt : WBt) + eoff;
  const int k0 = blockIdx.x * 64;
  const int n0 = blockIdx.y * 64;
  const int t = threadIdx.x;
  const int c4 = (t & 15) * 4;
  const int rb = (t >> 4) * 4;
#pragma unroll
  for (int rr = 0; rr < 4; ++rr) {
    const int r = rb + rr;
    const float4 v = *(const float4*)(w + (size_t)(k0 + r) * DDIM + n0 + c4);
    tile[(c4 + 0) * TP + r] = (bf16_t)v.x;
    tile[(c4 + 1) * TP + r] = (bf16_t)v.y;
    tile[(c4 + 2) * TP + r] = (bf16_t)v.z;
    tile[(c4 + 3) * TP + r] = (bf16_t)v.w;
  }
  __syncthreads();
  const int nl = t >> 2;
  const int kq = (t & 3) * 16;
  bf16_t* dst = wt + (size_t)(n0 + nl) * DDIM + k0 + kq;
#pragma unroll
  for (int j2 = 0; j2 < 2; ++j2) {
    bf16x8 u = *(const bf16x8*)(&tile[nl * TP + kq + j2 * 8]);
    *(bf16x8*)(dst + j2 * 8) = u;
  }
}

// ---------------- GEMM1 (all experts): hidden_e = relu(X @ W1_e + b1_e), bf16 ----------------
__global__ __launch_bounds__(256, 2)
void k_gemm_relu(const bf16_t* __restrict__ A, const bf16_t* __restrict__ W1t,
                 const float* __restrict__ b1, bf16_t* __restrict__ Hd)
{
  __shared__ __attribute__((aligned(16))) bf16_t As[128 * 32];
  __shared__ __attribute__((aligned(16))) bf16_t Bs[128 * 32];
  const int e = blockIdx.z;
  const bf16_t* Bt = W1t + (size_t)e * GK * GN;
  const float* bias = b1 + (size_t)e * GN;
  bf16_t* H = Hd + (size_t)e * TOKENS * GN;

  const int t = threadIdx.x;
  const int wave = t >> 6;
  const int lane = t & 63;
  const int m0 = blockIdx.x * 128;
  const int n0 = blockIdx.y * 128;
  const int wm = (wave >> 1) << 6;
  const int wn = (wave & 1) << 6;

  f32x4 acc[4][4] = {};

  const bf16_t* aP0 = A + (size_t)(m0 + (t >> 2)) * GK + (t & 3) * 8;
  const bf16_t* aP1 = aP0 + (size_t)64 * GK;
  const bf16_t* bP0 = Bt + (size_t)(n0 + (t >> 2)) * GK + (t & 3) * 8;
  const bf16_t* bP1 = bP0 + (size_t)64 * GK;
  bf16_t* lA0 = As + wave * 512;
  bf16_t* lA1 = As + 2048 + wave * 512;
  bf16_t* lB0 = Bs + wave * 512;
  bf16_t* lB1 = Bs + 2048 + wave * 512;

  const int fr = lane & 15;
  const int kq = (lane >> 4) * 8;

  for (int k0 = 0; k0 < GK; k0 += 32) {
    gld_lds16(aP0 + k0, lA0);
    gld_lds16(aP1 + k0, lA1);
    gld_lds16(bP0 + k0, lB0);
    gld_lds16(bP1 + k0, lB1);
    __syncthreads();
    bf16x8 afr[4], bfr[4];
#pragma unroll
    for (int i = 0; i < 4; ++i) {
      afr[i] = *(const bf16x8*)(As + (wm + i * 16 + fr) * 32 + kq);
      bfr[i] = *(const bf16x8*)(Bs + (wn + i * 16 + fr) * 32 + kq);
    }
#pragma unroll
    for (int i = 0; i < 4; ++i)
#pragma unroll
      for (int j = 0; j < 4; ++j)
        acc[i][j] = __builtin_amdgcn_mfma_f32_16x16x32_bf16(afr[i], bfr[j], acc[i][j], 0, 0, 0);
    __syncthreads();
  }

  const int col = lane & 15;
  const int rq  = (lane >> 4) * 4;
#pragma unroll
  for (int j = 0; j < 4; ++j) {
    const int gn = n0 + wn + j * 16 + col;
    const float bv = bias[gn];
#pragma unroll
    for (int i = 0; i < 4; ++i) {
      const int gm = m0 + wm + i * 16 + rq;
#pragma unroll
      for (int r = 0; r < 4; ++r) {
        float v = acc[i][j][r] + bv;
        v = v > 0.f ? v : 0.f;
        H[(size_t)(gm + r) * GN + gn] = (bf16_t)v;
      }
    }
  }
}

// ---------------- GEMM2 split-K over experts: P[ks] = sum_{e in half} c_e[m]*(hidden_e @ W2_e + b2_e) ----------------
// grid (32, 16, 2); z = expert-half. Each block writes its fp32 partial tile once.
#define ESPLIT 2
#define EPER   (NEXP / ESPLIT)
__global__ __launch_bounds__(256, 2)
void k_gemm2_split(const bf16_t* __restrict__ Hd, const bf16_t* __restrict__ W2t,
                   const float* __restrict__ b2,
                   const float* __restrict__ c0, const float* __restrict__ c1,
                   float* __restrict__ P)
{
  __shared__ __attribute__((aligned(16))) bf16_t As[128 * 32];
  __shared__ __attribute__((aligned(16))) bf16_t Bs[128 * 32];
  __shared__ float cs[EPER][128];
  __shared__ float bs[EPER][128];

  const int t = threadIdx.x;
  const int wave = t >> 6;
  const int lane = t & 63;
  const int m0 = blockIdx.x * 128;
  const int n0 = blockIdx.y * 128;
  const int ks = blockIdx.z;
  const int wm = (wave >> 1) << 6;
  const int wn = (wave & 1) << 6;

  const bool hi = (n0 >= HDIM);
  const float* cc = hi ? c1 : c0;
  float* Pp = P + (size_t)ks * TOKENS * DDIM;

#pragma unroll
  for (int idx = t; idx < EPER * 128; idx += 256) {
    const int e = idx >> 7, r = idx & 127;
    cs[e][r] = cc[(ks * EPER + e) * TOKENS + m0 + r];
    bs[e][r] = b2[(ks * EPER + e) * DDIM + n0 + r];
  }

  f32x4 fin[4][4] = {};

  const int fr = lane & 15;
  const int kq = (lane >> 4) * 8;
  const int rowOff = (t >> 2);
  const int kOff = (t & 3) * 8;
  bf16_t* lA0 = As + wave * 512;
  bf16_t* lA1 = As + 2048 + wave * 512;
  bf16_t* lB0 = Bs + wave * 512;
  bf16_t* lB1 = Bs + 2048 + wave * 512;

  for (int ee = 0; ee < EPER; ++ee) {
    const int e = ks * EPER + ee;
    const bf16_t* aP0 = Hd + (size_t)e * TOKENS * GK + (size_t)(m0 + rowOff) * GK + kOff;
    const bf16_t* aP1 = aP0 + (size_t)64 * GK;
    const bf16_t* bP0 = W2t + (size_t)e * GN * GK + (size_t)(n0 + rowOff) * GK + kOff;
    const bf16_t* bP1 = bP0 + (size_t)64 * GK;

    f32x4 acc[4][4] = {};
    for (int k0 = 0; k0 < GK; k0 += 32) {
      gld_lds16(aP0 + k0, lA0);
      gld_lds16(aP1 + k0, lA1);
      gld_lds16(bP0 + k0, lB0);
      gld_lds16(bP1 + k0, lB1);
      __syncthreads();
      bf16x8 afr[4], bfr[4];
#pragma unroll
      for (int i = 0; i < 4; ++i) {
        afr[i] = *(const bf16x8*)(As + (wm + i * 16 + fr) * 32 + kq);
        bfr[i] = *(const bf16x8*)(Bs + (wn + i * 16 + fr) * 32 + kq);
      }
#pragma unroll
      for (int i = 0; i < 4; ++i)
#pragma unroll
        for (int j = 0; j < 4; ++j)
          acc[i][j] = __builtin_amdgcn_mfma_f32_16x16x32_bf16(afr[i], bfr[j], acc[i][j], 0, 0, 0);
      __syncthreads();
    }

    const int colL = wn + (lane & 15);
    const int rqL  = wm + (lane >> 4) * 4;
#pragma unroll
    for (int j = 0; j < 4; ++j) {
      const float bv = bs[ee][colL + j * 16];
#pragma unroll
      for (int i = 0; i < 4; ++i) {
#pragma unroll
        for (int r = 0; r < 4; ++r) {
          const float ce = cs[ee][rqL + i * 16 + r];
          fin[i][j][r] += ce * (acc[i][j][r] + bv);
        }
      }
    }
  }

  const int col = lane & 15;
  const int rq  = (lane >> 4) * 4;
#pragma unroll
  for (int j = 0; j < 4; ++j) {
    const int gn = n0 + wn + j * 16 + col;
    float* obase = hi ? (Pp + (size_t)TOKENS * HDIM + (gn - HDIM)) : (Pp + gn);
#pragma unroll
    for (int i = 0; i < 4; ++i) {
      const int gm = m0 + wm + i * 16 + rq;
#pragma unroll
      for (int r = 0; r < 4; ++r)
        obase[(size_t)(gm + r) * HDIM] = fin[i][j][r];
    }
  }
}

// ---------------- reduce: out = P[0] + P[1] ----------------
__global__ __launch_bounds__(256)
void k_reduce(const float* __restrict__ P, float* __restrict__ out)
{
  const size_t i = ((size_t)blockIdx.x * 256 + threadIdx.x) * 4;
  const float4 a = *(const float4*)(P + i);
  const float4 b = *(const float4*)(P + (size_t)TOKENS * DDIM + i);
  float4 o; o.x = a.x + b.x; o.y = a.y + b.y; o.z = a.z + b.z; o.w = a.w + b.w;
  *(float4*)(out + i) = o;
}

// ---------------- legacy per-expert GEMM2 (small-ws fallback) ----------------
__global__ __launch_bounds__(256, 2)
void k_gemm_out(const bf16_t* __restrict__ A, const bf16_t* __restrict__ Bt,
                const float* __restrict__ bias,
                const float* __restrict__ c0, const float* __restrict__ c1,
                float* __restrict__ out0, float* __restrict__ out1, const int accum)
{
  __shared__ __attribute__((aligned(16))) bf16_t As[128 * 32];
  __shared__ __attribute__((aligned(16))) bf16_t Bs[128 * 32];
  const int t = threadIdx.x;
  const int wave = t >> 6;
  const int lane = t & 63;
  const int m0 = blockIdx.x * 128;
  const int n0 = blockIdx.y * 128;
  const int wm = (wave >> 1) << 6;
  const int wn = (wave & 1) << 6;

  f32x4 acc[4][4] = {};

  const bf16_t* aP0 = A + (size_t)(m0 + (t >> 2)) * GK + (t & 3) * 8;
  const bf16_t* aP1 = aP0 + (size_t)64 * GK;
  const bf16_t* bP0 = Bt + (size_t)(n0 + (t >> 2)) * GK + (t & 3) * 8;
  const bf16_t* bP1 = bP0 + (size_t)64 * GK;
  bf16_t* lA0 = As + wave * 512;
  bf16_t* lA1 = As + 2048 + wave * 512;
  bf16_t* lB0 = Bs + wave * 512;
  bf16_t* lB1 = Bs + 2048 + wave * 512;

  const int fr = lane & 15;
  const int kq = (lane >> 4) * 8;

  for (int k0 = 0; k0 < GK; k0 += 32) {
    gld_lds16(aP0 + k0, lA0);
    gld_lds16(aP1 + k0, lA1);
    gld_lds16(bP0 + k0, lB0);
    gld_lds16(bP1 + k0, lB1);
    __syncthreads();
    bf16x8 afr[4], bfr[4];
#pragma unroll
    for (int i = 0; i < 4; ++i) {
      afr[i] = *(const bf16x8*)(As + (wm + i * 16 + fr) * 32 + kq);
      bfr[i] = *(const bf16x8*)(Bs + (wn + i * 16 + fr) * 32 + kq);
    }
#pragma unroll
    for (int i = 0; i < 4; ++i)
#pragma unroll
      for (int j = 0; j < 4; ++j)
        acc[i][j] = __builtin_amdgcn_mfma_f32_16x16x32_bf16(afr[i], bfr[j], acc[i][j], 0, 0, 0);
    __syncthreads();
  }

  const int col = lane & 15;
  const int rq  = (lane >> 4) * 4;
#pragma unroll
  for (int j = 0; j < 4; ++j) {
    const int gn = n0 + wn + j * 16 + col;
    const float bv = bias[gn];
    const bool lo = gn < HDIM;
    float* obase = lo ? (out0 + gn) : (out1 + (gn - HDIM));
    const float* cc = lo ? c0 : c1;
#pragma unroll
    for (int i = 0; i < 4; ++i) {
      const int gmB = m0 + wm + i * 16 + rq;
#pragma unroll
      for (int r = 0; r < 4; ++r) {
        const int gm = gmB + r;
        float v = (acc[i][j][r] + bv) * cc[gm];
        float* dst = obase + (size_t)gm * HDIM;
        if (accum) v += *dst;
        *dst = v;
      }
    }
  }
}

extern "C" void kernel_launch(void* const* d_in, const int* in_sizes, int n_in,
                              void* d_out, int out_size, void* d_ws, size_t ws_size,
                              hipStream_t stream)
{
  const float* vec = (const float*)d_in[0];
  const float* Wg  = (const float*)d_in[1];
  const float* bg  = (const float*)d_in[2];
  const float* Wf  = (const float*)d_in[3];
  const float* bfv = (const float*)d_in[4];
  const float* W1  = (const float*)d_in[5];
  const float* b1  = (const float*)d_in[6];
  const float* W2  = (const float*)d_in[7];
  const float* b2  = (const float*)d_in[8];
  const float* wgt = (const float*)d_in[9];

  float* out0 = (float*)d_out;
  float* out1 = out0 + (size_t)TOKENS * HDIM;

  char* base = (char*)d_ws;
  const size_t XB = (size_t)TOKENS * DDIM * 2;        // 16 MiB
  const size_t HB = (size_t)NEXP * TOKENS * DDIM * 2; // 128 MiB
  const size_t WT = (size_t)NEXP * DDIM * DDIM * 2;   // 64 MiB each
  const size_t PB = (size_t)ESPLIT * TOKENS * DDIM * 4; // 64 MiB partials

  bf16_t* Xbf = (bf16_t*)base;
  float*  c0  = (float*)(base + XB);
  float*  c1  = c0 + (size_t)NEXP * TOKENS;
  size_t off = XB + 2 * (size_t)NEXP * TOKENS * 4;

  k_routing_cvt<<<dim3(TOKENS / 4), 256, 0, stream>>>(vec, Wg, bg, Wf, bfv, wgt, c0, c1, Xbf);

  if (ws_size >= off + HB + 2 * WT + PB) {
    bf16_t* hidden = (bf16_t*)(base + off);
    bf16_t* W1t    = (bf16_t*)(base + off + HB);
    bf16_t* W2t    = (bf16_t*)(base + off + HB + WT);
    float*  P      = (float*)(base + off + HB + 2 * WT);
    k_cvt_wt<<<dim3(32, 32, 2 * NEXP), 256, 0, stream>>>(W1, W2, W1t, W2t, NEXP);
    k_gemm_relu<<<dim3(32, 16, NEXP), 256, 0, stream>>>(Xbf, W1t, b1, hidden);
    k_gemm2_split<<<dim3(32, 16, ESPLIT), 256, 0, stream>>>(hidden, W2t, b2, c0, c1, P);
    k_reduce<<<dim3((TOKENS * DDIM) / 1024), 256, 0, stream>>>(P, out0);
  } else {
    // small-ws fallback: sequential per-expert with reused buffers
    bf16_t* hidden = (bf16_t*)(base + off);
    bf16_t* W1t    = hidden + (size_t)TOKENS * DDIM;
    bf16_t* W2t    = W1t + (size_t)DDIM * DDIM;
    for (int e = 0; e < NEXP; ++e) {
      k_cvt_wt<<<dim3(32, 32, 2), 256, 0, stream>>>(
          W1 + (size_t)e * DDIM * DDIM, W2 + (size_t)e * DDIM * DDIM, W1t, W2t, 1);
      k_gemm_relu<<<dim3(32, 16, 1), 256, 0, stream>>>(Xbf, W1t, b1 + (size_t)e * DDIM, hidden);
      k_gemm_out<<<dim3(32, 16), 256, 0, stream>>>(
          hidden, W2t, b2 + (size_t)e * DDIM,
          c0 + (size_t)e * TOKENS, c1 + (size_t)e * TOKENS, out0, out1, e > 0);
    }
  }
}